// Round 12
// baseline (218.552 us; speedup 1.0000x reference)
//
#include <hip/hip_runtime.h>
#include <stdint.h>

#define BB 2
#define TT 2048
#define DD 2048
#define NHD 16
#define KVH 8
#define HD 128
#define JC 4096          // qkv gemm output cols: q 2048 | k 1024 | v 1024
#define WIN 1024
#define SCALE_Q 0.08838834764831845f  // 1/sqrt(128)

typedef __attribute__((ext_vector_type(8))) short bf16x8;
typedef __attribute__((ext_vector_type(8))) unsigned short us8;
typedef __attribute__((ext_vector_type(4))) unsigned short us4;
typedef __attribute__((ext_vector_type(4))) float f32x4;
typedef __attribute__((ext_vector_type(16))) float f32x16;
typedef __attribute__((ext_vector_type(4))) unsigned int u32x4;

#define GAS __attribute__((address_space(1)))
#define LAS __attribute__((address_space(3)))

__device__ __forceinline__ unsigned short f2bf(float f) {
  unsigned u = __float_as_uint(f);
  u += 0x7FFFu + ((u >> 16) & 1u);   // RNE
  return (unsigned short)(u >> 16);
}
__device__ __forceinline__ float bf2f(unsigned short u) {
  return __uint_as_float(((unsigned)u) << 16);
}

__device__ __forceinline__ void gload16(const void* g, void* l) {
  __builtin_amdgcn_global_load_lds((const GAS unsigned int*)g, (LAS unsigned int*)l, 16, 0, 0);
}

#define VMCNT(n) asm volatile("s_waitcnt vmcnt(" #n ")" ::: "memory")

// ---------------- merged pre-pass: x->bf16 (ids<8192) + weight transposes ----------------
__global__ void __launch_bounds__(256) k_pre(
    const float4* __restrict__ x4, us4* __restrict__ xb,
    const float* __restrict__ qw, const float* __restrict__ kvw,
    const float* __restrict__ ow, unsigned short* __restrict__ Wt,
    unsigned short* __restrict__ Wt_o) {
  __shared__ float tile[32][33];
  int id = blockIdx.x;
  int tid = threadIdx.x;
  if (id < 8192) {               // x convert: 8192 * 256 float4
    int i = id * 256 + tid;
    float4 v = x4[i];
    us4 o;
    o[0] = f2bf(v.x); o[1] = f2bf(v.y); o[2] = f2bf(v.z); o[3] = f2bf(v.w);
    xb[i] = o;
    return;
  }
  const float* ib;
  unsigned short* ob;
  int ldin, c0, r0;
  int t = id - 8192;
  if (t < 8192) {                // q_w / kv_w transpose (32 z-batches of 4x64 tiles)
    int bx = t & 3, by = (t >> 2) & 63, z = t >> 8;
    ib = (z < 16) ? qw + (long)z * 2048 * 128 : kvw + (long)(z - 16) * 2048 * 128;
    ob = Wt + (long)z * 128 * 2048;
    ldin = 128;
    c0 = bx * 32; r0 = by * 32;
  } else {                       // o_w transpose (64x64 tiles)
    int u = t - 8192;
    ib = ow; ob = Wt_o; ldin = 2048;
    c0 = (u & 63) * 32; r0 = (u >> 6) * 32;
  }
  int tx = tid & 31, ty = tid >> 5;
#pragma unroll
  for (int i = 0; i < 4; i++)
    tile[ty + i * 8][tx] = ib[(long)(r0 + ty + i * 8) * ldin + c0 + tx];
  __syncthreads();
#pragma unroll
  for (int i = 0; i < 4; i++)
    ob[(long)(c0 + ty + i * 8) * 2048 + r0 + tx] = f2bf(tile[tx][ty + i * 8]);
}

// ---------------- bf16 GEMM: counted-vmcnt pipeline, per-wave (BM/2)x64 ----------------
template <int BM, int BN, int NWN, int THREADS, int NBUF, bool BF16OUT>
__global__ void __launch_bounds__(THREADS, 2) k_gemm9(
    const unsigned short* __restrict__ A, const unsigned short* __restrict__ Bt,
    void* __restrict__ Cv, int M, int Nn, int nby) {
  constexpr int KD = 2048;
  constexpr int NT = KD / 32;
  constexpr int ROWS = BM + BN;
  constexpr int RPI = THREADS / 4;     // rows per gload issue
  constexpr int IA = BM / RPI;
  constexpr int IPT = ROWS / RPI;      // gload issues per K-tile
  constexpr int MT = BM / 32;          // per-wave M tiles (BM/2 rows = MT x 16)
  constexpr int MT2 = MT / 2;
  __shared__ short lds[NBUF][ROWS * 32];

  int tid = threadIdx.x, lane = tid & 63, w = tid >> 6;
  int wm = w / NWN, wn = w % NWN;
  int id = blockIdx.x;
  int cpx = gridDim.x >> 3;
  id = (id & 7) * cpx + (id >> 3);     // XCD swizzle (grid % 8 == 0)
  int m0 = (id / nby) * BM, n0 = (id % nby) * BN;

  int srow = tid >> 2;
  int scol = ((tid & 3) ^ ((tid >> 3) & 3)) * 8;   // inverse-swizzled source
  const unsigned short* gA = A + (long)(m0 + srow) * KD + scol;
  const unsigned short* gB = Bt + (long)(n0 + srow) * KD + scol;

  auto STG = [&](int p, int ko, int j) {
    if (j < IA)
      gload16(gA + (long)j * RPI * KD + ko, &lds[p][(j * RPI + w * 16) * 32]);
    else
      gload16(gB + (long)(j - IA) * RPI * KD + ko,
              &lds[p][(BM + (j - IA) * RPI + w * 16) * 32]);
  };

  // frag read: phys chunk = (lane>>4) ^ ((lane>>1)&3)
  int frag = (lane & 15) * 32 + (((lane >> 4) ^ ((lane >> 1) & 3)) * 8);
  int abase = wm * (BM / 2) * 32 + frag;
  int bbase = (BM + wn * 64) * 32 + frag;

  f32x4 acc[MT][4] = {};
#pragma unroll
  for (int tt = 0; tt < NBUF - 1; ++tt)
#pragma unroll
    for (int j = 0; j < IPT; ++j) STG(tt, tt * 32, j);
  {
    constexpr int PW = IPT * (NBUF - 2);   // loads allowed in flight after prologue
    if constexpr (PW >= 8)      VMCNT(8);
    else if constexpr (PW == 6) VMCNT(6);
    else if constexpr (PW == 4) VMCNT(4);
    else                        VMCNT(0);
  }
  __builtin_amdgcn_s_barrier();

  int buf = 0, sp = NBUF - 1;
  for (int t = 0; t < NT; ++t) {
    const short* bufp = lds[buf];
    bool st = (t + NBUF - 1) < NT;
    int ko = (t + NBUF - 1) * 32;
    // ---- phase A: M-half 0 ----
    bf16x8 bfr[4], af[MT2];
#pragma unroll
    for (int ni = 0; ni < 4; ++ni)
      bfr[ni] = *(const bf16x8*)&bufp[bbase + ni * 16 * 32];
#pragma unroll
    for (int mi = 0; mi < MT2; ++mi)
      af[mi] = *(const bf16x8*)&bufp[abase + mi * 16 * 32];
    if (st) {
#pragma unroll
      for (int j = 0; j < IPT / 2; ++j) STG(sp, ko, j);
    }
    __builtin_amdgcn_s_barrier();
    asm volatile("s_waitcnt lgkmcnt(0)" ::: "memory");
    __builtin_amdgcn_sched_barrier(0);
    __builtin_amdgcn_s_setprio(1);
#pragma unroll
    for (int mi = 0; mi < MT2; ++mi)
#pragma unroll
      for (int ni = 0; ni < 4; ++ni)
        acc[mi][ni] = __builtin_amdgcn_mfma_f32_16x16x32_bf16(af[mi], bfr[ni], acc[mi][ni], 0, 0, 0);
    __builtin_amdgcn_s_setprio(0);
    __builtin_amdgcn_s_barrier();
    // ---- phase B: M-half 1 (B-frags reused from registers) ----
    bf16x8 af2[MT2];
#pragma unroll
    for (int mi = 0; mi < MT2; ++mi)
      af2[mi] = *(const bf16x8*)&bufp[abase + (MT2 + mi) * 16 * 32];
    if (st) {
#pragma unroll
      for (int j = IPT / 2; j < IPT; ++j) STG(sp, ko, j);
    }
    {
      int rem = NT - 2 - t;
      if (rem > NBUF - 2) rem = NBUF - 2;
      if (rem == 2) {
        if constexpr (IPT == 4) VMCNT(8); else VMCNT(12);
      } else if (rem == 1) {
        if constexpr (IPT == 4) VMCNT(4); else VMCNT(6);
      } else if (rem == 0) {
        VMCNT(0);
      }
    }
    __builtin_amdgcn_s_barrier();
    asm volatile("s_waitcnt lgkmcnt(0)" ::: "memory");
    __builtin_amdgcn_sched_barrier(0);
    __builtin_amdgcn_s_setprio(1);
#pragma unroll
    for (int mi = 0; mi < MT2; ++mi)
#pragma unroll
      for (int ni = 0; ni < 4; ++ni)
        acc[MT2 + mi][ni] = __builtin_amdgcn_mfma_f32_16x16x32_bf16(af2[mi], bfr[ni], acc[MT2 + mi][ni], 0, 0, 0);
    __builtin_amdgcn_s_setprio(0);
    __builtin_amdgcn_s_barrier();
    buf = (buf == NBUF - 1) ? 0 : buf + 1;
    sp = (sp == NBUF - 1) ? 0 : sp + 1;
  }

#pragma unroll
  for (int mi = 0; mi < MT; mi++)
#pragma unroll
    for (int ni = 0; ni < 4; ni++)
#pragma unroll
      for (int r = 0; r < 4; r++) {
        int row = m0 + wm * (BM / 2) + mi * 16 + (lane >> 4) * 4 + r;
        int col = n0 + wn * 64 + ni * 16 + (lane & 15);
        if constexpr (BF16OUT)
          ((unsigned short*)Cv)[(long)row * Nn + col] = f2bf(acc[mi][ni][r]);
        else
          ((float*)Cv)[(long)row * Nn + col] = acc[mi][ni][r];
      }
}

// ---------------- merged post-pass: RMSNorm+RoPE (ids<24576) + v transpose ----------------
__global__ void __launch_bounds__(256) k_post(
    const unsigned short* __restrict__ qkv, const float* __restrict__ qns,
    const float* __restrict__ kns, unsigned short* __restrict__ qb,
    unsigned short* __restrict__ kb, unsigned short* __restrict__ vbT) {
  int id = blockIdx.x;
  int tid = threadIdx.x;
  if (id < 24576) {   // norm+rope over B*T*24 rows, 4 rows/block
    int wid = tid >> 6, lane = tid & 63;
    long r = (long)id * 4 + wid;
    int b = (int)(r / (TT * 24));
    int rem = (int)(r % (TT * 24));
    int t = rem / 24, hd = rem % 24;
    const unsigned short* row = qkv + (long)(b * TT + t) * JC + (hd < 16 ? hd * HD : 2048 + (hd - 16) * HD);
    float f0 = bf2f(row[lane]), f1 = bf2f(row[lane + 64]);
    float ss = f0 * f0 + f1 * f1;
#pragma unroll
    for (int m = 1; m < 64; m <<= 1) ss += __shfl_xor(ss, m, 64);
    float rinv = rsqrtf(ss * (1.0f / 128.0f) + 1e-6f);
    const float* sc = (hd < 16) ? qns : kns;
    float y0 = f0 * rinv * (1.0f + sc[lane]);
    float y1 = f1 * rinv * (1.0f + sc[lane + 64]);
    float ts = exp2f((float)lane * (13.287712379549449f / 64.0f));
    float ang = (float)t / ts;
    float s, c;
    sincosf(ang, &s, &c);
    float o0 = y0 * c - y1 * s;
    float o1 = y1 * c + y0 * s;
    unsigned short* dst;
    if (hd < 16) {
      o0 *= SCALE_Q; o1 *= SCALE_Q;
      dst = qb + ((long)(b * NHD + hd) * TT + t) * HD;
    } else {
      dst = kb + ((long)(b * KVH + (hd - 16)) * TT + t) * HD;
    }
    dst[lane] = f2bf(o0);
    dst[lane + 64] = f2bf(o1);
    return;
  }
  // v transpose: 4096 tiles; in: qkv + 3072 (ld 4096), batches (b,kh) -> out vbT
  __shared__ unsigned short tile[32][33];
  int t4 = id - 24576;
  int bx = t4 & 3, by = (t4 >> 2) & 63, z = t4 >> 8;
  const unsigned short* ib = qkv + 3072 + (long)(z / 8) * 2048 * 4096 + (long)(z % 8) * 128;
  unsigned short* ob = vbT + (long)z * 128 * 2048;
  int c0 = bx * 32, r0 = by * 32;
  int tx = tid & 31, ty = tid >> 5;
#pragma unroll
  for (int i = 0; i < 4; i++)
    tile[ty + i * 8][tx] = ib[(long)(r0 + ty + i * 8) * 4096 + c0 + tx];
  __syncthreads();
#pragma unroll
  for (int i = 0; i < 4; i++)
    ob[(long)(c0 + ty + i * 8) * 2048 + r0 + tx] = tile[tx][ty + i * 8];
}

// ---------------- softcap: p = exp(50*tanh(x/50) - 50) = exp2(-144.2695/(1+exp2(.0577*x)))
template <bool FULL>
__device__ __forceinline__ void softcap16(const f32x16& s16, float* pr, float& lsum,
                                          int s_base, int tq, int g) {
#pragma unroll
  for (int r = 0; r < 16; r++) {
    float x = s16[r];
    float e2 = __builtin_amdgcn_exp2f(0.05770780163555853f * x);
    float p = __builtin_amdgcn_exp2f(-144.26950408889634f * __builtin_amdgcn_rcpf(1.0f + e2));
    if (!FULL) {
      int s = s_base + (r & 3) + 8 * (r >> 2) + 4 * g;
      bool valid = (s <= tq) && (s > tq - WIN);
      p = valid ? p : 0.0f;
    }
    lsum += p;
    pr[r] = p;
  }
}

// half-swap across lane-32 boundary
__device__ __forceinline__ void hswap(unsigned& a, unsigned& b, int g) {
  unsigned ax = (unsigned)__shfl_xor((int)a, 32, 64);
  unsigned bx = (unsigned)__shfl_xor((int)b, 32, 64);
  unsigned r0 = g ? bx : a;
  unsigned r1 = g ? b : ax;
  a = r0; b = r1;
}

// ---------------- flash attention v2 (R9-proven): QBLK=128 (4 waves x 32 q), KVBLK=64 ----
// grid 512 -> 2 blocks/CU, 8 waves/CU (2 waves/SIMD — the validated TLP floor).
// Swapped QK^T, fixed-max=50 softmax, in-register P^T via cvt_pk + half-swap.
__global__ void __launch_bounds__(256, 2) k_attn(
    const unsigned short* __restrict__ qb, const unsigned short* __restrict__ kb,
    const unsigned short* __restrict__ vbT, unsigned short* __restrict__ enc) {
  __shared__ short Kl[2][64][128];   // [buf][s][d], XOR-swizzled 16B chunks: c ^= (s&7)
  __shared__ short Vt[2][128][64];   // [buf][h][s], XOR-swizzled 16B chunks: c ^= (h&7)
  int tid = threadIdx.x, lane = tid & 63, w = tid >> 6;
  int g = lane >> 5, l31 = lane & 31;
  int id = blockIdx.x;
  int b = id >> 8;
  int rem = id & 255;
  int n = rem >> 4;
  int traw = rem & 15;
  int tile = b ? ((traw + 8) & 15) : traw;  // pair small+large work per CU slot
  int t0 = tile * 128;
  int kh = n >> 1;
  const unsigned short* qbase = qb + ((long)(b * NHD + n) * TT + t0 + w * 32) * HD;
  const unsigned short* kbase = kb + (long)(b * KVH + kh) * TT * HD;
  const unsigned short* vbase = vbT + (long)(b * KVH + kh) * HD * TT;

  bf16x8 bq[8];
  {
    const unsigned short* qp = qbase + (long)l31 * HD + g * 8;
#pragma unroll
    for (int kb8 = 0; kb8 < 8; kb8++)
      bq[kb8] = *(const bf16x8*)(qp + kb8 * 16);
  }

  f32x16 acc[4] = {};
  float lsum = 0.0f;
  int t0w = t0 + w * 32;
  int tq = t0w + l31;
  int s_begin = (t0 >= WIN) ? t0 - WIN : 0;
  int s_end = t0 + 128;

  auto STAGE = [&](int buf, int s0) {
#pragma unroll
    for (int i = 0; i < 4; i++) {
      int row = w * 16 + i * 4 + (lane >> 4);
      int c16 = (lane & 15) ^ (row & 7);
      gload16(kbase + (long)(s0 + row) * HD + c16 * 8, &Kl[buf][w * 16 + i * 4][0]);
    }
#pragma unroll
    for (int i = 0; i < 4; i++) {
      int row = w * 32 + i * 8 + (lane >> 3);
      int c16 = (lane & 7) ^ (row & 7);
      gload16(vbase + (long)row * TT + s0 + c16 * 8, &Vt[buf][w * 32 + i * 8][0]);
    }
  };

  STAGE(0, s_begin);
  __syncthreads();
  int cur = 0;
  for (int s0 = s_begin; s0 < s_end; s0 += 64) {
    if (s0 + 64 < s_end) STAGE(cur ^ 1, s0 + 64);
    bool live = (s0 <= t0w + 31) && (s0 + 63 >= t0w - (WIN - 1));
    if (live) {
      f32x16 sc2[2] = {};
#pragma unroll
      for (int sb = 0; sb < 2; sb++) {
        int srow = sb * 32 + l31;
#pragma unroll
        for (int kb8 = 0; kb8 < 8; kb8++) {
          bf16x8 ak = *(const bf16x8*)&Kl[cur][srow][8 * ((2 * kb8 + g) ^ (srow & 7))];
          sc2[sb] = __builtin_amdgcn_mfma_f32_32x32x16_bf16(ak, bq[kb8], sc2[sb], 0, 0, 0);
        }
      }
      bool full = (s0 + 63 <= t0w) && (s0 >= t0w + 31 - (WIN - 1));
      unsigned pw[4][4];
#pragma unroll
      for (int sb = 0; sb < 2; sb++) {
        float pr[16];
        if (full) softcap16<true>(sc2[sb], pr, lsum, 0, tq, g);
        else      softcap16<false>(sc2[sb], pr, lsum, s0 + sb * 32, tq, g);
        unsigned X[4], Y[4];
#pragma unroll
        for (int m = 0; m < 4; m++) {
          asm("v_cvt_pk_bf16_f32 %0, %1, %2" : "=v"(X[m]) : "v"(pr[4 * m]), "v"(pr[4 * m + 1]));
          asm("v_cvt_pk_bf16_f32 %0, %1, %2" : "=v"(Y[m]) : "v"(pr[4 * m + 2]), "v"(pr[4 * m + 3]));
        }
#pragma unroll
        for (int kl = 0; kl < 2; kl++) {
          hswap(X[2 * kl], X[2 * kl + 1], g);
          hswap(Y[2 * kl], Y[2 * kl + 1], g);
          pw[sb * 2 + kl][0] = X[2 * kl];
          pw[sb * 2 + kl][1] = Y[2 * kl];
          pw[sb * 2 + kl][2] = X[2 * kl + 1];
          pw[sb * 2 + kl][3] = Y[2 * kl + 1];
        }
      }
#pragma unroll
      for (int ks = 0; ks < 4; ks++) {
        u32x4 t4 = {pw[ks][0], pw[ks][1], pw[ks][2], pw[ks][3]};
        bf16x8 pb = __builtin_bit_cast(bf16x8, t4);
#pragma unroll
        for (int ht = 0; ht < 4; ht++) {
          int hrow = ht * 32 + l31;
          bf16x8 av = *(const bf16x8*)&Vt[cur][hrow][8 * ((2 * ks + g) ^ (hrow & 7))];
          acc[ht] = __builtin_amdgcn_mfma_f32_32x32x16_bf16(av, pb, acc[ht], 0, 0, 0);
        }
      }
    }
    __syncthreads();
    cur ^= 1;
  }

  lsum += __shfl_xor(lsum, 32, 64);
  float inv = __builtin_amdgcn_rcpf(lsum);
  unsigned short* dst = enc + ((long)(b * TT + tq) * NHD + n) * HD;
#pragma unroll
  for (int ht = 0; ht < 4; ht++)
#pragma unroll
    for (int r4 = 0; r4 < 4; r4++) {
      us4 o;
#pragma unroll
      for (int e = 0; e < 4; e++) o[e] = f2bf(acc[ht][r4 * 4 + e] * inv);
      *(us4*)(dst + ht * 32 + 8 * r4 + 4 * g) = o;
    }
}

extern "C" void kernel_launch(void* const* d_in, const int* in_sizes, int n_in,
                              void* d_out, int out_size, void* d_ws, size_t ws_size,
                              hipStream_t stream) {
  const float* x    = (const float*)d_in[0];
  const float* q_w  = (const float*)d_in[1];
  const float* kv_w = (const float*)d_in[2];
  const float* o_w  = (const float*)d_in[3];
  const float* qns  = (const float*)d_in[4];
  const float* kns  = (const float*)d_in[5];

  if (ws_size < (104ull << 20)) return;
  char* ws = (char*)d_ws;
  unsigned short* qkvb = (unsigned short*)(ws + 0);             // 32 MB bf16 (dead after post)
  unsigned short* enc  = (unsigned short*)(ws + 0);             // alias over dead qkvb
  unsigned short* x_bf = (unsigned short*)(ws + (64ll << 20));  // 16 MB (dead after gemm1)
  unsigned short* qb   = (unsigned short*)(ws + (64ll << 20));  // alias over dead x_bf
  unsigned short* Wt   = (unsigned short*)(ws + (80ll << 20));  // 16 MB (dead after gemm1)
  unsigned short* kb   = (unsigned short*)(ws + (80ll << 20));  // alias over dead Wt
  unsigned short* vbT  = (unsigned short*)(ws + (88ll << 20));  // alias over dead Wt
  unsigned short* Wt_o = (unsigned short*)(ws + (96ll << 20));  // 8 MB, persists

  // pre: x convert (8192) + q/kv wt transpose (8192) + o_w transpose (4096)
  k_pre<<<20480, 256, 0, stream>>>((const float4*)x, (us4*)x_bf, q_w, kv_w, o_w, Wt, Wt_o);
  // qkv = x @ W : 4096x4096, bf16 out, BM=256 BN=128, grid 16*32 = 512 (2 blocks/CU)
  k_gemm9<256, 128, 2, 256, 3, true><<<512, 256, 0, stream>>>(x_bf, Wt, qkvb, 4096, 4096, 32);
  // post: rmsnorm+rope (24576) + v transpose (4096)
  k_post<<<28672, 256, 0, stream>>>(qkvb, qns, kns, qb, kb, vbT);
  // attention -> enc (bf16), QBLK=128 / 4 waves, grid 2*16*16 = 512 (2 blocks/CU)
  k_attn<<<512, 256, 0, stream>>>(qb, kb, vbT, enc);
  // out = enc @ o_w : 4096x2048, fp32 to d_out, BM=128 BN=128, grid 32*16 = 512 (2 blocks/CU)
  k_gemm9<128, 128, 2, 256, 3, false><<<512, 256, 0, stream>>>(enc, Wt_o, (float*)d_out, 4096, 2048, 16);
}

// Round 13
// 210.559 us; speedup vs baseline: 1.0380x; 1.0380x over previous
//
#include <hip/hip_runtime.h>
#include <stdint.h>

#define BB 2
#define TT 2048
#define DD 2048
#define NHD 16
#define KVH 8
#define HD 128
#define JC 4096          // qkv gemm output cols: q 2048 | k 1024 | v 1024
#define WIN 1024
#define SCALE_Q 0.08838834764831845f  // 1/sqrt(128)

typedef __attribute__((ext_vector_type(8))) short bf16x8;
typedef __attribute__((ext_vector_type(8))) unsigned short us8;
typedef __attribute__((ext_vector_type(4))) unsigned short us4;
typedef __attribute__((ext_vector_type(4))) float f32x4;
typedef __attribute__((ext_vector_type(16))) float f32x16;
typedef __attribute__((ext_vector_type(4))) unsigned int u32x4;

#define GAS __attribute__((address_space(1)))
#define LAS __attribute__((address_space(3)))

__device__ __forceinline__ unsigned short f2bf(float f) {
  unsigned u = __float_as_uint(f);
  u += 0x7FFFu + ((u >> 16) & 1u);   // RNE
  return (unsigned short)(u >> 16);
}
__device__ __forceinline__ float bf2f(unsigned short u) {
  return __uint_as_float(((unsigned)u) << 16);
}

__device__ __forceinline__ void gload16(const void* g, void* l) {
  __builtin_amdgcn_global_load_lds((const GAS unsigned int*)g, (LAS unsigned int*)l, 16, 0, 0);
}

#define VMCNT(n) asm volatile("s_waitcnt vmcnt(" #n ")" ::: "memory")

// ---------------- merged pre-pass: x->bf16 (ids<8192) + weight transposes ----------------
__global__ void __launch_bounds__(256) k_pre(
    const float4* __restrict__ x4, us4* __restrict__ xb,
    const float* __restrict__ qw, const float* __restrict__ kvw,
    const float* __restrict__ ow, unsigned short* __restrict__ Wt,
    unsigned short* __restrict__ Wt_o) {
  __shared__ float tile[32][33];
  int id = blockIdx.x;
  int tid = threadIdx.x;
  if (id < 8192) {               // x convert: 8192 * 256 float4
    int i = id * 256 + tid;
    float4 v = x4[i];
    us4 o;
    o[0] = f2bf(v.x); o[1] = f2bf(v.y); o[2] = f2bf(v.z); o[3] = f2bf(v.w);
    xb[i] = o;
    return;
  }
  const float* ib;
  unsigned short* ob;
  int ldin, c0, r0;
  int t = id - 8192;
  if (t < 8192) {                // q_w / kv_w transpose (32 z-batches of 4x64 tiles)
    int bx = t & 3, by = (t >> 2) & 63, z = t >> 8;
    ib = (z < 16) ? qw + (long)z * 2048 * 128 : kvw + (long)(z - 16) * 2048 * 128;
    ob = Wt + (long)z * 128 * 2048;
    ldin = 128;
    c0 = bx * 32; r0 = by * 32;
  } else {                       // o_w transpose (64x64 tiles)
    int u = t - 8192;
    ib = ow; ob = Wt_o; ldin = 2048;
    c0 = (u & 63) * 32; r0 = (u >> 6) * 32;
  }
  int tx = tid & 31, ty = tid >> 5;
#pragma unroll
  for (int i = 0; i < 4; i++)
    tile[ty + i * 8][tx] = ib[(long)(r0 + ty + i * 8) * ldin + c0 + tx];
  __syncthreads();
#pragma unroll
  for (int i = 0; i < 4; i++)
    ob[(long)(c0 + ty + i * 8) * 2048 + r0 + tx] = f2bf(tile[tx][ty + i * 8]);
}

// ---------------- bf16 GEMM 8-phase (m201 geometry): 256x256 tile, BK=64 ----------------
// 8 waves (2M x 4N), per-wave 128x64. LDS 128 KiB = 2 K-tile buffers x 4 regions
// {A rows0-127, A rows128-255, B rows0-127, B rows128-255} of [128][64] bf16.
// Phase q of tile t: ds_read A-quadrant (mi=2q,2q+1; + all B at q0, held in regs),
// stage one region (death-ordered: t+1's A at q0/q1 into other buf; t+2's B at q2/q3
// into this buf -- t's B died after q0), barrier, lgkm0, 16 MFMA, barrier.
// VMCNT(4) once per K-tile (t+1's 8 issues landed, t+2's 4 B stay in flight).
// Swizzle: phys 16B-chunk = chunk ^ (row&7), both sides (involution).
template <bool BF16OUT>
__global__ void __launch_bounds__(512, 2) k_gemm8p(
    const unsigned short* __restrict__ A, const unsigned short* __restrict__ Bt,
    void* __restrict__ Cv, int Nn, int nby) {
  constexpr int KD = 2048;
  constexpr int NT = KD / 64;
  __shared__ short lds[2 * 4 * 8192];   // [buf][region][128*64]

  int tid = threadIdx.x, lane = tid & 63, w = tid >> 6;
  int wm = w >> 2, wn = w & 3;
  int id = blockIdx.x;
  int cpx = gridDim.x >> 3;
  id = (id & 7) * cpx + (id >> 3);      // XCD swizzle (grid % 8 == 0)
  int m0 = (id / nby) * 256, n0 = (id % nby) * 256;

  // staging: thread covers row (tid>>3) of a 64-row issue, phys chunk tid&7;
  // source logical chunk = (tid&7) ^ ((tid>>3)&7)  (involution)
  int srow = tid >> 3;
  int scol = ((tid & 7) ^ ((tid >> 3) & 7)) * 8;
  const unsigned short* gA = A + (long)(m0 + srow) * KD + scol;
  const unsigned short* gB = Bt + (long)(n0 + srow) * KD + scol;
  int wrow = w * 8 * 64;                // wave's LDS base rows (8 rows x 64 shorts)

  auto STG = [&](int p, int ko, int r) {  // region r: 0=Alo 1=Ahi 2=Blo 3=Bhi
    const unsigned short* gsrc = (r < 2) ? gA + (long)(r * 128) * KD + ko
                                         : gB + (long)((r - 2) * 128) * KD + ko;
    short* dst = &lds[p * 32768 + r * 8192 + wrow];
#pragma unroll
    for (int i = 0; i < 2; ++i)
      gload16(gsrc + (long)(i * 64) * KD, dst + i * 4096);
  };

  // frag read: row&7 == lane&7 for all frags; phys chunk = (kk*4 + (lane>>4)) ^ (lane&7)
  int c0 = ((lane >> 4) ^ (lane & 7)) * 8;
  int abase = wm * 8192 + (lane & 15) * 64;
  int bbase = 16384 + (wn >> 1) * 8192 + ((wn & 1) * 64 + (lane & 15)) * 64;

  f32x4 acc[8][4] = {};
  // prologue: tile0 all 4 regions (8 issues), tile1 B regions (4 issues)
#pragma unroll
  for (int r = 0; r < 4; ++r) STG(0, 0, r);
  STG(1, 64, 2);
  STG(1, 64, 3);
  VMCNT(4);
  __builtin_amdgcn_s_barrier();

  bf16x8 bf[4][2];
  for (int t = 0; t < NT; ++t) {
    const short* bp = &lds[(t & 1) * 32768];
    int sb1 = (t + 1) & 1, sb2 = t & 1;
    int ko1 = (t + 1) * 64, ko2 = (t + 2) * 64;
    bool s1 = (t + 1) < NT, s2 = (t + 2) < NT;
#pragma unroll
    for (int q = 0; q < 4; ++q) {
      bf16x8 af[2][2];
#pragma unroll
      for (int m2 = 0; m2 < 2; ++m2)
#pragma unroll
        for (int kk = 0; kk < 2; ++kk)
          af[m2][kk] = *(const bf16x8*)&bp[abase + (q * 2 + m2) * 16 * 64 + (c0 ^ (kk * 32))];
      if (q == 0) {
#pragma unroll
        for (int ni = 0; ni < 4; ++ni)
#pragma unroll
          for (int kk = 0; kk < 2; ++kk)
            bf[ni][kk] = *(const bf16x8*)&bp[bbase + ni * 16 * 64 + (c0 ^ (kk * 32))];
      }
      if (q == 0) { if (s1) STG(sb1, ko1, 0); }
      else if (q == 1) { if (s1) STG(sb1, ko1, 1); }
      else if (q == 2) { if (s2) STG(sb2, ko2, 2); }
      else {
        if (s2) { STG(sb2, ko2, 3); VMCNT(4); }
        else if (s1) VMCNT(0);
      }
      __builtin_amdgcn_s_barrier();
      asm volatile("s_waitcnt lgkmcnt(0)" ::: "memory");
      __builtin_amdgcn_sched_barrier(0);
      __builtin_amdgcn_s_setprio(1);
#pragma unroll
      for (int m2 = 0; m2 < 2; ++m2)
#pragma unroll
        for (int ni = 0; ni < 4; ++ni)
#pragma unroll
          for (int kk = 0; kk < 2; ++kk)
            acc[q * 2 + m2][ni] = __builtin_amdgcn_mfma_f32_16x16x32_bf16(
                af[m2][kk], bf[ni][kk], acc[q * 2 + m2][ni], 0, 0, 0);
      __builtin_amdgcn_s_setprio(0);
      __builtin_amdgcn_s_barrier();
    }
  }

#pragma unroll
  for (int mi = 0; mi < 8; mi++)
#pragma unroll
    for (int ni = 0; ni < 4; ni++)
#pragma unroll
      for (int r = 0; r < 4; r++) {
        int row = m0 + wm * 128 + mi * 16 + (lane >> 4) * 4 + r;
        int col = n0 + wn * 64 + ni * 16 + (lane & 15);
        if constexpr (BF16OUT)
          ((unsigned short*)Cv)[(long)row * Nn + col] = f2bf(acc[mi][ni][r]);
        else
          ((float*)Cv)[(long)row * Nn + col] = acc[mi][ni][r];
      }
}

// ---------------- bf16 GEMM (2-phase, proven): counted-vmcnt, per-wave (BM/2)x64 ------
template <int BM, int BN, int NWN, int THREADS, int NBUF, bool BF16OUT>
__global__ void __launch_bounds__(THREADS, 2) k_gemm9(
    const unsigned short* __restrict__ A, const unsigned short* __restrict__ Bt,
    void* __restrict__ Cv, int M, int Nn, int nby) {
  constexpr int KD = 2048;
  constexpr int NT = KD / 32;
  constexpr int ROWS = BM + BN;
  constexpr int RPI = THREADS / 4;
  constexpr int IA = BM / RPI;
  constexpr int IPT = ROWS / RPI;
  constexpr int MT = BM / 32;
  constexpr int MT2 = MT / 2;
  __shared__ short lds[NBUF][ROWS * 32];

  int tid = threadIdx.x, lane = tid & 63, w = tid >> 6;
  int wm = w / NWN, wn = w % NWN;
  int id = blockIdx.x;
  int cpx = gridDim.x >> 3;
  id = (id & 7) * cpx + (id >> 3);
  int m0 = (id / nby) * BM, n0 = (id % nby) * BN;

  int srow = tid >> 2;
  int scol = ((tid & 3) ^ ((tid >> 3) & 3)) * 8;
  const unsigned short* gA = A + (long)(m0 + srow) * KD + scol;
  const unsigned short* gB = Bt + (long)(n0 + srow) * KD + scol;

  auto STG = [&](int p, int ko, int j) {
    if (j < IA)
      gload16(gA + (long)j * RPI * KD + ko, &lds[p][(j * RPI + w * 16) * 32]);
    else
      gload16(gB + (long)(j - IA) * RPI * KD + ko,
              &lds[p][(BM + (j - IA) * RPI + w * 16) * 32]);
  };

  int frag = (lane & 15) * 32 + (((lane >> 4) ^ ((lane >> 1) & 3)) * 8);
  int abase = wm * (BM / 2) * 32 + frag;
  int bbase = (BM + wn * 64) * 32 + frag;

  f32x4 acc[MT][4] = {};
#pragma unroll
  for (int tt = 0; tt < NBUF - 1; ++tt)
#pragma unroll
    for (int j = 0; j < IPT; ++j) STG(tt, tt * 32, j);
  {
    constexpr int PW = IPT * (NBUF - 2);
    if constexpr (PW >= 8)      VMCNT(8);
    else if constexpr (PW == 6) VMCNT(6);
    else if constexpr (PW == 4) VMCNT(4);
    else                        VMCNT(0);
  }
  __builtin_amdgcn_s_barrier();

  int buf = 0, sp = NBUF - 1;
  for (int t = 0; t < NT; ++t) {
    const short* bufp = lds[buf];
    bool st = (t + NBUF - 1) < NT;
    int ko = (t + NBUF - 1) * 32;
    bf16x8 bfr[4], af[MT2];
#pragma unroll
    for (int ni = 0; ni < 4; ++ni)
      bfr[ni] = *(const bf16x8*)&bufp[bbase + ni * 16 * 32];
#pragma unroll
    for (int mi = 0; mi < MT2; ++mi)
      af[mi] = *(const bf16x8*)&bufp[abase + mi * 16 * 32];
    if (st) {
#pragma unroll
      for (int j = 0; j < IPT / 2; ++j) STG(sp, ko, j);
    }
    __builtin_amdgcn_s_barrier();
    asm volatile("s_waitcnt lgkmcnt(0)" ::: "memory");
    __builtin_amdgcn_sched_barrier(0);
    __builtin_amdgcn_s_setprio(1);
#pragma unroll
    for (int mi = 0; mi < MT2; ++mi)
#pragma unroll
      for (int ni = 0; ni < 4; ++ni)
        acc[mi][ni] = __builtin_amdgcn_mfma_f32_16x16x32_bf16(af[mi], bfr[ni], acc[mi][ni], 0, 0, 0);
    __builtin_amdgcn_s_setprio(0);
    __builtin_amdgcn_s_barrier();
    bf16x8 af2[MT2];
#pragma unroll
    for (int mi = 0; mi < MT2; ++mi)
      af2[mi] = *(const bf16x8*)&bufp[abase + (MT2 + mi) * 16 * 32];
    if (st) {
#pragma unroll
      for (int j = IPT / 2; j < IPT; ++j) STG(sp, ko, j);
    }
    {
      int rem = NT - 2 - t;
      if (rem > NBUF - 2) rem = NBUF - 2;
      if (rem == 2) {
        if constexpr (IPT == 4) VMCNT(8); else VMCNT(12);
      } else if (rem == 1) {
        if constexpr (IPT == 4) VMCNT(4); else VMCNT(6);
      } else if (rem == 0) {
        VMCNT(0);
      }
    }
    __builtin_amdgcn_s_barrier();
    asm volatile("s_waitcnt lgkmcnt(0)" ::: "memory");
    __builtin_amdgcn_sched_barrier(0);
    __builtin_amdgcn_s_setprio(1);
#pragma unroll
    for (int mi = 0; mi < MT2; ++mi)
#pragma unroll
      for (int ni = 0; ni < 4; ++ni)
        acc[MT2 + mi][ni] = __builtin_amdgcn_mfma_f32_16x16x32_bf16(af2[mi], bfr[ni], acc[MT2 + mi][ni], 0, 0, 0);
    __builtin_amdgcn_s_setprio(0);
    __builtin_amdgcn_s_barrier();
    buf = (buf == NBUF - 1) ? 0 : buf + 1;
    sp = (sp == NBUF - 1) ? 0 : sp + 1;
  }

#pragma unroll
  for (int mi = 0; mi < MT; mi++)
#pragma unroll
    for (int ni = 0; ni < 4; ni++)
#pragma unroll
      for (int r = 0; r < 4; r++) {
        int row = m0 + wm * (BM / 2) + mi * 16 + (lane >> 4) * 4 + r;
        int col = n0 + wn * 64 + ni * 16 + (lane & 15);
        if constexpr (BF16OUT)
          ((unsigned short*)Cv)[(long)row * Nn + col] = f2bf(acc[mi][ni][r]);
        else
          ((float*)Cv)[(long)row * Nn + col] = acc[mi][ni][r];
      }
}

// ---------------- merged post-pass: RMSNorm+RoPE (ids<24576) + v transpose ----------------
__global__ void __launch_bounds__(256) k_post(
    const unsigned short* __restrict__ qkv, const float* __restrict__ qns,
    const float* __restrict__ kns, unsigned short* __restrict__ qb,
    unsigned short* __restrict__ kb, unsigned short* __restrict__ vbT) {
  int id = blockIdx.x;
  int tid = threadIdx.x;
  if (id < 24576) {
    int wid = tid >> 6, lane = tid & 63;
    long r = (long)id * 4 + wid;
    int b = (int)(r / (TT * 24));
    int rem = (int)(r % (TT * 24));
    int t = rem / 24, hd = rem % 24;
    const unsigned short* row = qkv + (long)(b * TT + t) * JC + (hd < 16 ? hd * HD : 2048 + (hd - 16) * HD);
    float f0 = bf2f(row[lane]), f1 = bf2f(row[lane + 64]);
    float ss = f0 * f0 + f1 * f1;
#pragma unroll
    for (int m = 1; m < 64; m <<= 1) ss += __shfl_xor(ss, m, 64);
    float rinv = rsqrtf(ss * (1.0f / 128.0f) + 1e-6f);
    const float* sc = (hd < 16) ? qns : kns;
    float y0 = f0 * rinv * (1.0f + sc[lane]);
    float y1 = f1 * rinv * (1.0f + sc[lane + 64]);
    float ts = exp2f((float)lane * (13.287712379549449f / 64.0f));
    float ang = (float)t / ts;
    float s, c;
    sincosf(ang, &s, &c);
    float o0 = y0 * c - y1 * s;
    float o1 = y1 * c + y0 * s;
    unsigned short* dst;
    if (hd < 16) {
      o0 *= SCALE_Q; o1 *= SCALE_Q;
      dst = qb + ((long)(b * NHD + hd) * TT + t) * HD;
    } else {
      dst = kb + ((long)(b * KVH + (hd - 16)) * TT + t) * HD;
    }
    dst[lane] = f2bf(o0);
    dst[lane + 64] = f2bf(o1);
    return;
  }
  __shared__ unsigned short tile[32][33];
  int t4 = id - 24576;
  int bx = t4 & 3, by = (t4 >> 2) & 63, z = t4 >> 8;
  const unsigned short* ib = qkv + 3072 + (long)(z / 8) * 2048 * 4096 + (long)(z % 8) * 128;
  unsigned short* ob = vbT + (long)z * 128 * 2048;
  int c0 = bx * 32, r0 = by * 32;
  int tx = tid & 31, ty = tid >> 5;
#pragma unroll
  for (int i = 0; i < 4; i++)
    tile[ty + i * 8][tx] = ib[(long)(r0 + ty + i * 8) * 4096 + c0 + tx];
  __syncthreads();
#pragma unroll
  for (int i = 0; i < 4; i++)
    ob[(long)(c0 + ty + i * 8) * 2048 + r0 + tx] = tile[tx][ty + i * 8];
}

// ---------------- softcap: p = exp(50*tanh(x/50) - 50) = exp2(-144.2695/(1+exp2(.0577*x)))
template <bool FULL>
__device__ __forceinline__ void softcap16(const f32x16& s16, float* pr, float& lsum,
                                          int s_base, int tq, int g) {
#pragma unroll
  for (int r = 0; r < 16; r++) {
    float x = s16[r];
    float e2 = __builtin_amdgcn_exp2f(0.05770780163555853f * x);
    float p = __builtin_amdgcn_exp2f(-144.26950408889634f * __builtin_amdgcn_rcpf(1.0f + e2));
    if (!FULL) {
      int s = s_base + (r & 3) + 8 * (r >> 2) + 4 * g;
      bool valid = (s <= tq) && (s > tq - WIN);
      p = valid ? p : 0.0f;
    }
    lsum += p;
    pr[r] = p;
  }
}

__device__ __forceinline__ void hswap(unsigned& a, unsigned& b, int g) {
  unsigned ax = (unsigned)__shfl_xor((int)a, 32, 64);
  unsigned bx = (unsigned)__shfl_xor((int)b, 32, 64);
  unsigned r0 = g ? bx : a;
  unsigned r1 = g ? b : ax;
  a = r0; b = r1;
}

// ---------------- flash attention v2 (proven): QBLK=128 (4 waves x 32 q), KVBLK=64 ----
__global__ void __launch_bounds__(256, 2) k_attn(
    const unsigned short* __restrict__ qb, const unsigned short* __restrict__ kb,
    const unsigned short* __restrict__ vbT, unsigned short* __restrict__ enc) {
  __shared__ short Kl[2][64][128];
  __shared__ short Vt[2][128][64];
  int tid = threadIdx.x, lane = tid & 63, w = tid >> 6;
  int g = lane >> 5, l31 = lane & 31;
  int id = blockIdx.x;
  int b = id >> 8;
  int rem = id & 255;
  int n = rem >> 4;
  int traw = rem & 15;
  int tile = b ? ((traw + 8) & 15) : traw;
  int t0 = tile * 128;
  int kh = n >> 1;
  const unsigned short* qbase = qb + ((long)(b * NHD + n) * TT + t0 + w * 32) * HD;
  const unsigned short* kbase = kb + (long)(b * KVH + kh) * TT * HD;
  const unsigned short* vbase = vbT + (long)(b * KVH + kh) * HD * TT;

  bf16x8 bq[8];
  {
    const unsigned short* qp = qbase + (long)l31 * HD + g * 8;
#pragma unroll
    for (int kb8 = 0; kb8 < 8; kb8++)
      bq[kb8] = *(const bf16x8*)(qp + kb8 * 16);
  }

  f32x16 acc[4] = {};
  float lsum = 0.0f;
  int t0w = t0 + w * 32;
  int tq = t0w + l31;
  int s_begin = (t0 >= WIN) ? t0 - WIN : 0;
  int s_end = t0 + 128;

  auto STAGE = [&](int buf, int s0) {
#pragma unroll
    for (int i = 0; i < 4; i++) {
      int row = w * 16 + i * 4 + (lane >> 4);
      int c16 = (lane & 15) ^ (row & 7);
      gload16(kbase + (long)(s0 + row) * HD + c16 * 8, &Kl[buf][w * 16 + i * 4][0]);
    }
#pragma unroll
    for (int i = 0; i < 4; i++) {
      int row = w * 32 + i * 8 + (lane >> 3);
      int c16 = (lane & 7) ^ (row & 7);
      gload16(vbase + (long)row * TT + s0 + c16 * 8, &Vt[buf][w * 32 + i * 8][0]);
    }
  };

  STAGE(0, s_begin);
  __syncthreads();
  int cur = 0;
  for (int s0 = s_begin; s0 < s_end; s0 += 64) {
    if (s0 + 64 < s_end) STAGE(cur ^ 1, s0 + 64);
    bool live = (s0 <= t0w + 31) && (s0 + 63 >= t0w - (WIN - 1));
    if (live) {
      f32x16 sc2[2] = {};
#pragma unroll
      for (int sb = 0; sb < 2; sb++) {
        int srow = sb * 32 + l31;
#pragma unroll
        for (int kb8 = 0; kb8 < 8; kb8++) {
          bf16x8 ak = *(const bf16x8*)&Kl[cur][srow][8 * ((2 * kb8 + g) ^ (srow & 7))];
          sc2[sb] = __builtin_amdgcn_mfma_f32_32x32x16_bf16(ak, bq[kb8], sc2[sb], 0, 0, 0);
        }
      }
      bool full = (s0 + 63 <= t0w) && (s0 >= t0w + 31 - (WIN - 1));
      unsigned pw[4][4];
#pragma unroll
      for (int sb = 0; sb < 2; sb++) {
        float pr[16];
        if (full) softcap16<true>(sc2[sb], pr, lsum, 0, tq, g);
        else      softcap16<false>(sc2[sb], pr, lsum, s0 + sb * 32, tq, g);
        unsigned X[4], Y[4];
#pragma unroll
        for (int m = 0; m < 4; m++) {
          asm("v_cvt_pk_bf16_f32 %0, %1, %2" : "=v"(X[m]) : "v"(pr[4 * m]), "v"(pr[4 * m + 1]));
          asm("v_cvt_pk_bf16_f32 %0, %1, %2" : "=v"(Y[m]) : "v"(pr[4 * m + 2]), "v"(pr[4 * m + 3]));
        }
#pragma unroll
        for (int kl = 0; kl < 2; kl++) {
          hswap(X[2 * kl], X[2 * kl + 1], g);
          hswap(Y[2 * kl], Y[2 * kl + 1], g);
          pw[sb * 2 + kl][0] = X[2 * kl];
          pw[sb * 2 + kl][1] = Y[2 * kl];
          pw[sb * 2 + kl][2] = X[2 * kl + 1];
          pw[sb * 2 + kl][3] = Y[2 * kl + 1];
        }
      }
#pragma unroll
      for (int ks = 0; ks < 4; ks++) {
        u32x4 t4 = {pw[ks][0], pw[ks][1], pw[ks][2], pw[ks][3]};
        bf16x8 pb = __builtin_bit_cast(bf16x8, t4);
#pragma unroll
        for (int ht = 0; ht < 4; ht++) {
          int hrow = ht * 32 + l31;
          bf16x8 av = *(const bf16x8*)&Vt[cur][hrow][8 * ((2 * ks + g) ^ (hrow & 7))];
          acc[ht] = __builtin_amdgcn_mfma_f32_32x32x16_bf16(av, pb, acc[ht], 0, 0, 0);
        }
      }
    }
    __syncthreads();
    cur ^= 1;
  }

  lsum += __shfl_xor(lsum, 32, 64);
  float inv = __builtin_amdgcn_rcpf(lsum);
  unsigned short* dst = enc + ((long)(b * TT + tq) * NHD + n) * HD;
#pragma unroll
  for (int ht = 0; ht < 4; ht++)
#pragma unroll
    for (int r4 = 0; r4 < 4; r4++) {
      us4 o;
#pragma unroll
      for (int e = 0; e < 4; e++) o[e] = f2bf(acc[ht][r4 * 4 + e] * inv);
      *(us4*)(dst + ht * 32 + 8 * r4 + 4 * g) = o;
    }
}

extern "C" void kernel_launch(void* const* d_in, const int* in_sizes, int n_in,
                              void* d_out, int out_size, void* d_ws, size_t ws_size,
                              hipStream_t stream) {
  const float* x    = (const float*)d_in[0];
  const float* q_w  = (const float*)d_in[1];
  const float* kv_w = (const float*)d_in[2];
  const float* o_w  = (const float*)d_in[3];
  const float* qns  = (const float*)d_in[4];
  const float* kns  = (const float*)d_in[5];

  if (ws_size < (104ull << 20)) return;
  char* ws = (char*)d_ws;
  unsigned short* qkvb = (unsigned short*)(ws + 0);             // 32 MB bf16 (dead after post)
  unsigned short* enc  = (unsigned short*)(ws + 0);             // alias over dead qkvb
  unsigned short* x_bf = (unsigned short*)(ws + (64ll << 20));  // 16 MB (dead after gemm1)
  unsigned short* qb   = (unsigned short*)(ws + (64ll << 20));  // alias over dead x_bf
  unsigned short* Wt   = (unsigned short*)(ws + (80ll << 20));  // 16 MB (dead after gemm1)
  unsigned short* kb   = (unsigned short*)(ws + (80ll << 20));  // alias over dead Wt
  unsigned short* vbT  = (unsigned short*)(ws + (88ll << 20));  // alias over dead Wt
  unsigned short* Wt_o = (unsigned short*)(ws + (96ll << 20));  // 8 MB, persists

  // pre: x convert (8192) + q/kv wt transpose (8192) + o_w transpose (4096)
  k_pre<<<20480, 256, 0, stream>>>((const float4*)x, (us4*)x_bf, q_w, kv_w, o_w, Wt, Wt_o);
  // qkv = x @ W : 4096x4096, bf16 out, 256x256 8-phase, grid 16*16 = 256 (1 block/CU)
  k_gemm8p<true><<<256, 512, 0, stream>>>(x_bf, Wt, qkvb, 4096, 16);
  // post: rmsnorm+rope (24576) + v transpose (4096)
  k_post<<<28672, 256, 0, stream>>>(qkvb, qns, kns, qb, kb, vbT);
  // attention -> enc (bf16), QBLK=128 / 4 waves, grid 2*16*16 = 512 (2 blocks/CU)
  k_attn<<<512, 256, 0, stream>>>(qb, kb, vbT, enc);
  // out = enc @ o_w : 4096x2048, fp32 to d_out, BM=128 BN=128, grid 32*16 = 512
  k_gemm9<128, 128, 2, 256, 3, false><<<512, 256, 0, stream>>>(enc, Wt_o, (float*)d_out, 4096, 2048, 16);
}

// Round 14
// 210.055 us; speedup vs baseline: 1.0404x; 1.0024x over previous
//
#include <hip/hip_runtime.h>
#include <stdint.h>

#define BB 2
#define TT 2048
#define DD 2048
#define NHD 16
#define KVH 8
#define HD 128
#define JC 4096          // qkv gemm output cols: q 2048 | k 1024 | v 1024
#define WIN 1024
#define SCALE_Q 0.08838834764831845f  // 1/sqrt(128)

typedef __attribute__((ext_vector_type(8))) short bf16x8;
typedef __attribute__((ext_vector_type(8))) unsigned short us8;
typedef __attribute__((ext_vector_type(4))) unsigned short us4;
typedef __attribute__((ext_vector_type(4))) float f32x4;
typedef __attribute__((ext_vector_type(16))) float f32x16;
typedef __attribute__((ext_vector_type(4))) unsigned int u32x4;

#define GAS __attribute__((address_space(1)))
#define LAS __attribute__((address_space(3)))

__device__ __forceinline__ unsigned short f2bf(float f) {
  unsigned u = __float_as_uint(f);
  u += 0x7FFFu + ((u >> 16) & 1u);   // RNE
  return (unsigned short)(u >> 16);
}
__device__ __forceinline__ float bf2f(unsigned short u) {
  return __uint_as_float(((unsigned)u) << 16);
}

__device__ __forceinline__ void gload16(const void* g, void* l) {
  __builtin_amdgcn_global_load_lds((const GAS unsigned int*)g, (LAS unsigned int*)l, 16, 0, 0);
}

#define VMCNT(n) asm volatile("s_waitcnt vmcnt(" #n ")" ::: "memory")

// ---------------- merged pre-pass: x->bf16 (ids<8192) + weight transposes ----------------
__global__ void __launch_bounds__(256) k_pre(
    const float4* __restrict__ x4, us4* __restrict__ xb,
    const float* __restrict__ qw, const float* __restrict__ kvw,
    const float* __restrict__ ow, unsigned short* __restrict__ Wt,
    unsigned short* __restrict__ Wt_o) {
  __shared__ float tile[32][33];
  int id = blockIdx.x;
  int tid = threadIdx.x;
  if (id < 8192) {               // x convert: 8192 * 256 float4
    int i = id * 256 + tid;
    float4 v = x4[i];
    us4 o;
    o[0] = f2bf(v.x); o[1] = f2bf(v.y); o[2] = f2bf(v.z); o[3] = f2bf(v.w);
    xb[i] = o;
    return;
  }
  const float* ib;
  unsigned short* ob;
  int ldin, c0, r0;
  int t = id - 8192;
  if (t < 8192) {                // q_w / kv_w transpose (32 z-batches of 4x64 tiles)
    int bx = t & 3, by = (t >> 2) & 63, z = t >> 8;
    ib = (z < 16) ? qw + (long)z * 2048 * 128 : kvw + (long)(z - 16) * 2048 * 128;
    ob = Wt + (long)z * 128 * 2048;
    ldin = 128;
    c0 = bx * 32; r0 = by * 32;
  } else {                       // o_w transpose (64x64 tiles)
    int u = t - 8192;
    ib = ow; ob = Wt_o; ldin = 2048;
    c0 = (u & 63) * 32; r0 = (u >> 6) * 32;
  }
  int tx = tid & 31, ty = tid >> 5;
#pragma unroll
  for (int i = 0; i < 4; i++)
    tile[ty + i * 8][tx] = ib[(long)(r0 + ty + i * 8) * ldin + c0 + tx];
  __syncthreads();
#pragma unroll
  for (int i = 0; i < 4; i++)
    ob[(long)(c0 + ty + i * 8) * 2048 + r0 + tx] = f2bf(tile[tx][ty + i * 8]);
}

// ---------------- bf16 GEMM 8-phase (m201 geometry): 256x256 tile, BK=64 ----------------
template <bool BF16OUT>
__global__ void __launch_bounds__(512, 2) k_gemm8p(
    const unsigned short* __restrict__ A, const unsigned short* __restrict__ Bt,
    void* __restrict__ Cv, int Nn, int nby) {
  constexpr int KD = 2048;
  constexpr int NT = KD / 64;
  __shared__ short lds[2 * 4 * 8192];   // [buf][region][128*64]

  int tid = threadIdx.x, lane = tid & 63, w = tid >> 6;
  int wm = w >> 2, wn = w & 3;
  int id = blockIdx.x;
  int cpx = gridDim.x >> 3;
  id = (id & 7) * cpx + (id >> 3);      // XCD swizzle (grid % 8 == 0)
  int m0 = (id / nby) * 256, n0 = (id % nby) * 256;

  int srow = tid >> 3;
  int scol = ((tid & 7) ^ ((tid >> 3) & 7)) * 8;
  const unsigned short* gA = A + (long)(m0 + srow) * KD + scol;
  const unsigned short* gB = Bt + (long)(n0 + srow) * KD + scol;
  int wrow = w * 8 * 64;

  auto STG = [&](int p, int ko, int r) {  // region r: 0=Alo 1=Ahi 2=Blo 3=Bhi
    const unsigned short* gsrc = (r < 2) ? gA + (long)(r * 128) * KD + ko
                                         : gB + (long)((r - 2) * 128) * KD + ko;
    short* dst = &lds[p * 32768 + r * 8192 + wrow];
#pragma unroll
    for (int i = 0; i < 2; ++i)
      gload16(gsrc + (long)(i * 64) * KD, dst + i * 4096);
  };

  int c0 = ((lane >> 4) ^ (lane & 7)) * 8;
  int abase = wm * 8192 + (lane & 15) * 64;
  int bbase = 16384 + (wn >> 1) * 8192 + ((wn & 1) * 64 + (lane & 15)) * 64;

  f32x4 acc[8][4] = {};
#pragma unroll
  for (int r = 0; r < 4; ++r) STG(0, 0, r);
  STG(1, 64, 2);
  STG(1, 64, 3);
  VMCNT(4);
  __builtin_amdgcn_s_barrier();

  bf16x8 bf[4][2];
  for (int t = 0; t < NT; ++t) {
    const short* bp = &lds[(t & 1) * 32768];
    int sb1 = (t + 1) & 1, sb2 = t & 1;
    int ko1 = (t + 1) * 64, ko2 = (t + 2) * 64;
    bool s1 = (t + 1) < NT, s2 = (t + 2) < NT;
#pragma unroll
    for (int q = 0; q < 4; ++q) {
      bf16x8 af[2][2];
#pragma unroll
      for (int m2 = 0; m2 < 2; ++m2)
#pragma unroll
        for (int kk = 0; kk < 2; ++kk)
          af[m2][kk] = *(const bf16x8*)&bp[abase + (q * 2 + m2) * 16 * 64 + (c0 ^ (kk * 32))];
      if (q == 0) {
#pragma unroll
        for (int ni = 0; ni < 4; ++ni)
#pragma unroll
          for (int kk = 0; kk < 2; ++kk)
            bf[ni][kk] = *(const bf16x8*)&bp[bbase + ni * 16 * 64 + (c0 ^ (kk * 32))];
      }
      if (q == 0) { if (s1) STG(sb1, ko1, 0); }
      else if (q == 1) { if (s1) STG(sb1, ko1, 1); }
      else if (q == 2) { if (s2) STG(sb2, ko2, 2); }
      else {
        if (s2) { STG(sb2, ko2, 3); VMCNT(4); }
        else if (s1) VMCNT(0);
      }
      __builtin_amdgcn_s_barrier();
      asm volatile("s_waitcnt lgkmcnt(0)" ::: "memory");
      __builtin_amdgcn_sched_barrier(0);
      __builtin_amdgcn_s_setprio(1);
#pragma unroll
      for (int m2 = 0; m2 < 2; ++m2)
#pragma unroll
        for (int ni = 0; ni < 4; ++ni)
#pragma unroll
          for (int kk = 0; kk < 2; ++kk)
            acc[q * 2 + m2][ni] = __builtin_amdgcn_mfma_f32_16x16x32_bf16(
                af[m2][kk], bf[ni][kk], acc[q * 2 + m2][ni], 0, 0, 0);
      __builtin_amdgcn_s_setprio(0);
      __builtin_amdgcn_s_barrier();
    }
  }

#pragma unroll
  for (int mi = 0; mi < 8; mi++)
#pragma unroll
    for (int ni = 0; ni < 4; ni++)
#pragma unroll
      for (int r = 0; r < 4; r++) {
        int row = m0 + wm * 128 + mi * 16 + (lane >> 4) * 4 + r;
        int col = n0 + wn * 64 + ni * 16 + (lane & 15);
        if constexpr (BF16OUT)
          ((unsigned short*)Cv)[(long)row * Nn + col] = f2bf(acc[mi][ni][r]);
        else
          ((float*)Cv)[(long)row * Nn + col] = acc[mi][ni][r];
      }
}

// ---------------- bf16 GEMM (2-phase, proven): counted-vmcnt, per-wave (BM/2)x64 ------
template <int BM, int BN, int NWN, int THREADS, int NBUF, bool BF16OUT>
__global__ void __launch_bounds__(THREADS, 2) k_gemm9(
    const unsigned short* __restrict__ A, const unsigned short* __restrict__ Bt,
    void* __restrict__ Cv, int M, int Nn, int nby) {
  constexpr int KD = 2048;
  constexpr int NT = KD / 32;
  constexpr int ROWS = BM + BN;
  constexpr int RPI = THREADS / 4;
  constexpr int IA = BM / RPI;
  constexpr int IPT = ROWS / RPI;
  constexpr int MT = BM / 32;
  constexpr int MT2 = MT / 2;
  __shared__ short lds[NBUF][ROWS * 32];

  int tid = threadIdx.x, lane = tid & 63, w = tid >> 6;
  int wm = w / NWN, wn = w % NWN;
  int id = blockIdx.x;
  int cpx = gridDim.x >> 3;
  id = (id & 7) * cpx + (id >> 3);
  int m0 = (id / nby) * BM, n0 = (id % nby) * BN;

  int srow = tid >> 2;
  int scol = ((tid & 3) ^ ((tid >> 3) & 3)) * 8;
  const unsigned short* gA = A + (long)(m0 + srow) * KD + scol;
  const unsigned short* gB = Bt + (long)(n0 + srow) * KD + scol;

  auto STG = [&](int p, int ko, int j) {
    if (j < IA)
      gload16(gA + (long)j * RPI * KD + ko, &lds[p][(j * RPI + w * 16) * 32]);
    else
      gload16(gB + (long)(j - IA) * RPI * KD + ko,
              &lds[p][(BM + (j - IA) * RPI + w * 16) * 32]);
  };

  int frag = (lane & 15) * 32 + (((lane >> 4) ^ ((lane >> 1) & 3)) * 8);
  int abase = wm * (BM / 2) * 32 + frag;
  int bbase = (BM + wn * 64) * 32 + frag;

  f32x4 acc[MT][4] = {};
#pragma unroll
  for (int tt = 0; tt < NBUF - 1; ++tt)
#pragma unroll
    for (int j = 0; j < IPT; ++j) STG(tt, tt * 32, j);
  {
    constexpr int PW = IPT * (NBUF - 2);
    if constexpr (PW >= 8)      VMCNT(8);
    else if constexpr (PW == 6) VMCNT(6);
    else if constexpr (PW == 4) VMCNT(4);
    else                        VMCNT(0);
  }
  __builtin_amdgcn_s_barrier();

  int buf = 0, sp = NBUF - 1;
  for (int t = 0; t < NT; ++t) {
    const short* bufp = lds[buf];
    bool st = (t + NBUF - 1) < NT;
    int ko = (t + NBUF - 1) * 32;
    bf16x8 bfr[4], af[MT2];
#pragma unroll
    for (int ni = 0; ni < 4; ++ni)
      bfr[ni] = *(const bf16x8*)&bufp[bbase + ni * 16 * 32];
#pragma unroll
    for (int mi = 0; mi < MT2; ++mi)
      af[mi] = *(const bf16x8*)&bufp[abase + mi * 16 * 32];
    if (st) {
#pragma unroll
      for (int j = 0; j < IPT / 2; ++j) STG(sp, ko, j);
    }
    __builtin_amdgcn_s_barrier();
    asm volatile("s_waitcnt lgkmcnt(0)" ::: "memory");
    __builtin_amdgcn_sched_barrier(0);
    __builtin_amdgcn_s_setprio(1);
#pragma unroll
    for (int mi = 0; mi < MT2; ++mi)
#pragma unroll
      for (int ni = 0; ni < 4; ++ni)
        acc[mi][ni] = __builtin_amdgcn_mfma_f32_16x16x32_bf16(af[mi], bfr[ni], acc[mi][ni], 0, 0, 0);
    __builtin_amdgcn_s_setprio(0);
    __builtin_amdgcn_s_barrier();
    bf16x8 af2[MT2];
#pragma unroll
    for (int mi = 0; mi < MT2; ++mi)
      af2[mi] = *(const bf16x8*)&bufp[abase + (MT2 + mi) * 16 * 32];
    if (st) {
#pragma unroll
      for (int j = IPT / 2; j < IPT; ++j) STG(sp, ko, j);
    }
    {
      int rem = NT - 2 - t;
      if (rem > NBUF - 2) rem = NBUF - 2;
      if (rem == 2) {
        if constexpr (IPT == 4) VMCNT(8); else VMCNT(12);
      } else if (rem == 1) {
        if constexpr (IPT == 4) VMCNT(4); else VMCNT(6);
      } else if (rem == 0) {
        VMCNT(0);
      }
    }
    __builtin_amdgcn_s_barrier();
    asm volatile("s_waitcnt lgkmcnt(0)" ::: "memory");
    __builtin_amdgcn_sched_barrier(0);
    __builtin_amdgcn_s_setprio(1);
#pragma unroll
    for (int mi = 0; mi < MT2; ++mi)
#pragma unroll
      for (int ni = 0; ni < 4; ++ni)
        acc[MT2 + mi][ni] = __builtin_amdgcn_mfma_f32_16x16x32_bf16(af2[mi], bfr[ni], acc[MT2 + mi][ni], 0, 0, 0);
    __builtin_amdgcn_s_setprio(0);
    __builtin_amdgcn_s_barrier();
    buf = (buf == NBUF - 1) ? 0 : buf + 1;
    sp = (sp == NBUF - 1) ? 0 : sp + 1;
  }

#pragma unroll
  for (int mi = 0; mi < MT; mi++)
#pragma unroll
    for (int ni = 0; ni < 4; ni++)
#pragma unroll
      for (int r = 0; r < 4; r++) {
        int row = m0 + wm * (BM / 2) + mi * 16 + (lane >> 4) * 4 + r;
        int col = n0 + wn * 64 + ni * 16 + (lane & 15);
        if constexpr (BF16OUT)
          ((unsigned short*)Cv)[(long)row * Nn + col] = f2bf(acc[mi][ni][r]);
        else
          ((float*)Cv)[(long)row * Nn + col] = acc[mi][ni][r];
      }
}

// ---------------- merged post-pass: RMSNorm+RoPE (ids<24576) + v transpose ----------------
__global__ void __launch_bounds__(256) k_post(
    const unsigned short* __restrict__ qkv, const float* __restrict__ qns,
    const float* __restrict__ kns, unsigned short* __restrict__ qb,
    unsigned short* __restrict__ kb, unsigned short* __restrict__ vbT) {
  int id = blockIdx.x;
  int tid = threadIdx.x;
  if (id < 24576) {
    int wid = tid >> 6, lane = tid & 63;
    long r = (long)id * 4 + wid;
    int b = (int)(r / (TT * 24));
    int rem = (int)(r % (TT * 24));
    int t = rem / 24, hd = rem % 24;
    const unsigned short* row = qkv + (long)(b * TT + t) * JC + (hd < 16 ? hd * HD : 2048 + (hd - 16) * HD);
    float f0 = bf2f(row[lane]), f1 = bf2f(row[lane + 64]);
    float ss = f0 * f0 + f1 * f1;
#pragma unroll
    for (int m = 1; m < 64; m <<= 1) ss += __shfl_xor(ss, m, 64);
    float rinv = rsqrtf(ss * (1.0f / 128.0f) + 1e-6f);
    const float* sc = (hd < 16) ? qns : kns;
    float y0 = f0 * rinv * (1.0f + sc[lane]);
    float y1 = f1 * rinv * (1.0f + sc[lane + 64]);
    float ts = exp2f((float)lane * (13.287712379549449f / 64.0f));
    float ang = (float)t / ts;
    float s, c;
    sincosf(ang, &s, &c);
    float o0 = y0 * c - y1 * s;
    float o1 = y1 * c + y0 * s;
    unsigned short* dst;
    if (hd < 16) {
      o0 *= SCALE_Q; o1 *= SCALE_Q;
      dst = qb + ((long)(b * NHD + hd) * TT + t) * HD;
    } else {
      dst = kb + ((long)(b * KVH + (hd - 16)) * TT + t) * HD;
    }
    dst[lane] = f2bf(o0);
    dst[lane + 64] = f2bf(o1);
    return;
  }
  __shared__ unsigned short tile[32][33];
  int t4 = id - 24576;
  int bx = t4 & 3, by = (t4 >> 2) & 63, z = t4 >> 8;
  const unsigned short* ib = qkv + 3072 + (long)(z / 8) * 2048 * 4096 + (long)(z % 8) * 128;
  unsigned short* ob = vbT + (long)z * 128 * 2048;
  int c0 = bx * 32, r0 = by * 32;
  int tx = tid & 31, ty = tid >> 5;
#pragma unroll
  for (int i = 0; i < 4; i++)
    tile[ty + i * 8][tx] = ib[(long)(r0 + ty + i * 8) * 4096 + c0 + tx];
  __syncthreads();
#pragma unroll
  for (int i = 0; i < 4; i++)
    ob[(long)(c0 + ty + i * 8) * 2048 + r0 + tx] = tile[tx][ty + i * 8];
}

// ---------------- softcap: p = exp(50*tanh(x/50) - 50) = exp2(-144.2695/(1+exp2(.0577*x)))
template <bool FULL>
__device__ __forceinline__ void softcap16(const f32x16& s16, float* pr, float& lsum,
                                          int s_base, int tq, int g) {
#pragma unroll
  for (int r = 0; r < 16; r++) {
    float x = s16[r];
    float e2 = __builtin_amdgcn_exp2f(0.05770780163555853f * x);
    float p = __builtin_amdgcn_exp2f(-144.26950408889634f * __builtin_amdgcn_rcpf(1.0f + e2));
    if (!FULL) {
      int s = s_base + (r & 3) + 8 * (r >> 2) + 4 * g;
      bool valid = (s <= tq) && (s > tq - WIN);
      p = valid ? p : 0.0f;
    }
    lsum += p;
    pr[r] = p;
  }
}

__device__ __forceinline__ void hswap(unsigned& a, unsigned& b, int g) {
  unsigned ax = (unsigned)__shfl_xor((int)a, 32, 64);
  unsigned bx = (unsigned)__shfl_xor((int)b, 32, 64);
  unsigned r0 = g ? bx : a;
  unsigned r1 = g ? b : ax;
  a = r0; b = r1;
}

// ---------------- flash attention v2c: counted-vmcnt prefetch (no per-iter drain) ------
// QBLK=128 (4 waves x 32 q), KVBLK=64, grid 512 -> 2 blocks/CU, 8 waves/CU.
// Change vs v2: __syncthreads() (which drains vmcnt(0), serializing the prefetch issued
// the same iteration) is replaced by {VMCNT(8); s_barrier} -- tile t's loads were issued
// one full iteration ago, so waiting "all but the 8 just-issued" suffices; t+1's loads
// stay in flight across the barrier. Races: staged buf was last read 2 barriers ago
// (after lgkmcnt(0)); cross-wave visibility = own vmcnt + barrier (gemm9 pattern).
__global__ void __launch_bounds__(256, 2) k_attn(
    const unsigned short* __restrict__ qb, const unsigned short* __restrict__ kb,
    const unsigned short* __restrict__ vbT, unsigned short* __restrict__ enc) {
  __shared__ short Kl[2][64][128];
  __shared__ short Vt[2][128][64];
  int tid = threadIdx.x, lane = tid & 63, w = tid >> 6;
  int g = lane >> 5, l31 = lane & 31;
  int id = blockIdx.x;
  int b = id >> 8;
  int rem = id & 255;
  int n = rem >> 4;
  int traw = rem & 15;
  int tile = b ? ((traw + 8) & 15) : traw;
  int t0 = tile * 128;
  int kh = n >> 1;
  const unsigned short* qbase = qb + ((long)(b * NHD + n) * TT + t0 + w * 32) * HD;
  const unsigned short* kbase = kb + (long)(b * KVH + kh) * TT * HD;
  const unsigned short* vbase = vbT + (long)(b * KVH + kh) * HD * TT;

  bf16x8 bq[8];
  {
    const unsigned short* qp = qbase + (long)l31 * HD + g * 8;
#pragma unroll
    for (int kb8 = 0; kb8 < 8; kb8++)
      bq[kb8] = *(const bf16x8*)(qp + kb8 * 16);
  }

  f32x16 acc[4] = {};
  float lsum = 0.0f;
  int t0w = t0 + w * 32;
  int tq = t0w + l31;
  int s_begin = (t0 >= WIN) ? t0 - WIN : 0;
  int s_end = t0 + 128;

  auto STAGE = [&](int buf, int s0) {
#pragma unroll
    for (int i = 0; i < 4; i++) {
      int row = w * 16 + i * 4 + (lane >> 4);
      int c16 = (lane & 15) ^ (row & 7);
      gload16(kbase + (long)(s0 + row) * HD + c16 * 8, &Kl[buf][w * 16 + i * 4][0]);
    }
#pragma unroll
    for (int i = 0; i < 4; i++) {
      int row = w * 32 + i * 8 + (lane >> 3);
      int c16 = (lane & 7) ^ (row & 7);
      gload16(vbase + (long)row * TT + s0 + c16 * 8, &Vt[buf][w * 32 + i * 8][0]);
    }
  };

  STAGE(0, s_begin);
  int cur = 0;
  for (int s0 = s_begin; s0 < s_end; s0 += 64) {
    bool more = (s0 + 64 < s_end);
    if (more) {
      STAGE(cur ^ 1, s0 + 64);   // 8 issues in flight across the barrier
      VMCNT(8);                  // tile t's 8 loads (issued last iter) have landed
    } else {
      VMCNT(0);                  // no new issue: drain to guarantee tile t landed
    }
    __builtin_amdgcn_s_barrier();
    bool live = (s0 <= t0w + 31) && (s0 + 63 >= t0w - (WIN - 1));
    if (live) {
      f32x16 sc2[2] = {};
#pragma unroll
      for (int sb = 0; sb < 2; sb++) {
        int srow = sb * 32 + l31;
#pragma unroll
        for (int kb8 = 0; kb8 < 8; kb8++) {
          bf16x8 ak = *(const bf16x8*)&Kl[cur][srow][8 * ((2 * kb8 + g) ^ (srow & 7))];
          sc2[sb] = __builtin_amdgcn_mfma_f32_32x32x16_bf16(ak, bq[kb8], sc2[sb], 0, 0, 0);
        }
      }
      bool full = (s0 + 63 <= t0w) && (s0 >= t0w + 31 - (WIN - 1));
      unsigned pw[4][4];
#pragma unroll
      for (int sb = 0; sb < 2; sb++) {
        float pr[16];
        if (full) softcap16<true>(sc2[sb], pr, lsum, 0, tq, g);
        else      softcap16<false>(sc2[sb], pr, lsum, s0 + sb * 32, tq, g);
        unsigned X[4], Y[4];
#pragma unroll
        for (int m = 0; m < 4; m++) {
          asm("v_cvt_pk_bf16_f32 %0, %1, %2" : "=v"(X[m]) : "v"(pr[4 * m]), "v"(pr[4 * m + 1]));
          asm("v_cvt_pk_bf16_f32 %0, %1, %2" : "=v"(Y[m]) : "v"(pr[4 * m + 2]), "v"(pr[4 * m + 3]));
        }
#pragma unroll
        for (int kl = 0; kl < 2; kl++) {
          hswap(X[2 * kl], X[2 * kl + 1], g);
          hswap(Y[2 * kl], Y[2 * kl + 1], g);
          pw[sb * 2 + kl][0] = X[2 * kl];
          pw[sb * 2 + kl][1] = Y[2 * kl];
          pw[sb * 2 + kl][2] = X[2 * kl + 1];
          pw[sb * 2 + kl][3] = Y[2 * kl + 1];
        }
      }
#pragma unroll
      for (int ks = 0; ks < 4; ks++) {
        u32x4 t4 = {pw[ks][0], pw[ks][1], pw[ks][2], pw[ks][3]};
        bf16x8 pb = __builtin_bit_cast(bf16x8, t4);
#pragma unroll
        for (int ht = 0; ht < 4; ht++) {
          int hrow = ht * 32 + l31;
          bf16x8 av = *(const bf16x8*)&Vt[cur][hrow][8 * ((2 * ks + g) ^ (hrow & 7))];
          acc[ht] = __builtin_amdgcn_mfma_f32_32x32x16_bf16(av, pb, acc[ht], 0, 0, 0);
        }
      }
    }
    asm volatile("s_waitcnt lgkmcnt(0)" ::: "memory");
    __builtin_amdgcn_s_barrier();
    cur ^= 1;
  }

  lsum += __shfl_xor(lsum, 32, 64);
  float inv = __builtin_amdgcn_rcpf(lsum);
  unsigned short* dst = enc + ((long)(b * TT + tq) * NHD + n) * HD;
#pragma unroll
  for (int ht = 0; ht < 4; ht++)
#pragma unroll
    for (int r4 = 0; r4 < 4; r4++) {
      us4 o;
#pragma unroll
      for (int e = 0; e < 4; e++) o[e] = f2bf(acc[ht][r4 * 4 + e] * inv);
      *(us4*)(dst + ht * 32 + 8 * r4 + 4 * g) = o;
    }
}

extern "C" void kernel_launch(void* const* d_in, const int* in_sizes, int n_in,
                              void* d_out, int out_size, void* d_ws, size_t ws_size,
                              hipStream_t stream) {
  const float* x    = (const float*)d_in[0];
  const float* q_w  = (const float*)d_in[1];
  const float* kv_w = (const float*)d_in[2];
  const float* o_w  = (const float*)d_in[3];
  const float* qns  = (const float*)d_in[4];
  const float* kns  = (const float*)d_in[5];

  if (ws_size < (104ull << 20)) return;
  char* ws = (char*)d_ws;
  unsigned short* qkvb = (unsigned short*)(ws + 0);             // 32 MB bf16 (dead after post)
  unsigned short* enc  = (unsigned short*)(ws + 0);             // alias over dead qkvb
  unsigned short* x_bf = (unsigned short*)(ws + (64ll << 20));  // 16 MB (dead after gemm1)
  unsigned short* qb   = (unsigned short*)(ws + (64ll << 20));  // alias over dead x_bf
  unsigned short* Wt   = (unsigned short*)(ws + (80ll << 20));  // 16 MB (dead after gemm1)
  unsigned short* kb   = (unsigned short*)(ws + (80ll << 20));  // alias over dead Wt
  unsigned short* vbT  = (unsigned short*)(ws + (88ll << 20));  // alias over dead Wt
  unsigned short* Wt_o = (unsigned short*)(ws + (96ll << 20));  // 8 MB, persists

  // pre: x convert (8192) + q/kv wt transpose (8192) + o_w transpose (4096)
  k_pre<<<20480, 256, 0, stream>>>((const float4*)x, (us4*)x_bf, q_w, kv_w, o_w, Wt, Wt_o);
  // qkv = x @ W : 4096x4096, bf16 out, 256x256 8-phase, grid 16*16 = 256 (1 block/CU)
  k_gemm8p<true><<<256, 512, 0, stream>>>(x_bf, Wt, qkvb, 4096, 16);
  // post: rmsnorm+rope (24576) + v transpose (4096)
  k_post<<<28672, 256, 0, stream>>>(qkvb, qns, kns, qb, kb, vbT);
  // attention -> enc (bf16), QBLK=128 / 4 waves, grid 2*16*16 = 512 (2 blocks/CU)
  k_attn<<<512, 256, 0, stream>>>(qb, kb, vbT, enc);
  // out = enc @ o_w : 4096x2048, fp32 to d_out, BM=128 BN=128, grid 32*16 = 512
  k_gemm9<128, 128, 2, 256, 3, false><<<512, 256, 0, stream>>>(enc, Wt_o, (float*)d_out, 4096, 2048, 16);
}